// Round 1
// baseline (148.828 us; speedup 1.0000x reference)
//
#include <hip/hip_runtime.h>

// RandomShift: reflect-mode variable padding gather.
// in_: (N,T,F) fp32, in_lens: (N,) i32, pad: (2,N) i32
// out: (N,TP,F) fp32 followed by out_lens (N,) stored as fp32 (harness reads
// the concatenated output buffer as a single fp32 array).

#define N_  16
#define T_  4096
#define F_  256
#define TP_ 6552          // T + 2*int(0.3*T)
#define F4_ (F_ / 4)      // 64 float4 per row

__global__ __launch_bounds__(256) void random_shift_kernel(
    const float* __restrict__ in_,
    const int*   __restrict__ in_lens,
    const int*   __restrict__ pad,
    float*       __restrict__ out)
{
    const int i = blockIdx.x * blockDim.x + threadIdx.x;  // float4 index

    // Tail: out_lens as float (16 values right after the (N,TP,F) block).
    if (i < N_) {
        const int len = in_lens[i];
        const int ol  = len + pad[i] + pad[N_ + i];
        out[(size_t)N_ * TP_ * F_ + i] = (float)ol;
    }

    const int total = N_ * TP_ * F4_;
    if (i >= total) return;

    const int f4  = i & (F4_ - 1);
    const int row = i >> 6;            // (n, t) row index
    const int t   = row % TP_;
    const int n   = row / TP_;

    const int pad0 = pad[n];
    const int pad1 = pad[N_ + n];
    const int len  = in_lens[n];
    const int out_len = len + pad0 + pad1;

    float4 v = make_float4(0.f, 0.f, 0.f, 0.f);
    if (t < out_len) {
        int src;
        if (t < pad0)             src = pad0 - t;                 // left reflect
        else if (t < pad0 + len)  src = t - pad0;                 // middle
        else                      src = 2 * len + pad0 - t - 2;   // right reflect
        src = min(max(src, 0), T_ - 1);
        const float4* inrow =
            (const float4*)(in_ + ((size_t)n * T_ + src) * F_);
        v = inrow[f4];
    }
    ((float4*)out)[i] = v;
}

extern "C" void kernel_launch(void* const* d_in, const int* in_sizes, int n_in,
                              void* d_out, int out_size, void* d_ws, size_t ws_size,
                              hipStream_t stream) {
    const float* in_     = (const float*)d_in[0];
    const int*   in_lens = (const int*)d_in[1];
    const int*   pad     = (const int*)d_in[2];
    float*       out     = (float*)d_out;

    const int total  = N_ * TP_ * F4_;          // 6,709,248 float4s
    const int block  = 256;
    const int grid   = (total + block - 1) / block;
    random_shift_kernel<<<grid, block, 0, stream>>>(in_, in_lens, pad, out);
}